// Round 8
// baseline (1314.046 us; speedup 1.0000x reference)
//
#include <hip/hip_runtime.h>

#define C 16
#define TAPS 27
#define NCONV 17
#define LISTCAP 98304   // 35 sigma above expected ~88.5K actives
#define CBS 64          // conv block = 1 wave

// ---- weight transpose: W[l][co][ci][tap] -> Wt[l][tap][ci][co] ----
__global__ void transpose_w_kernel(const float* __restrict__ W, float* __restrict__ Wt) {
    int i = blockIdx.x * blockDim.x + threadIdx.x;
    const int total = NCONV * TAPS * C * C;
    if (i >= total) return;
    int co = i & 15;
    int ci = (i >> 4) & 15;
    int rest = i >> 8;
    int tap = rest % TAPS;
    int l = rest / TAPS;
    Wt[i] = W[(((long)l * C + co) * C + ci) * TAPS + tap];
}

// ---- x: NCDHW -> NDHWC ----
__global__ void transpose_in_kernel(const float* __restrict__ x, float* __restrict__ xt, int n) {
    int v = blockIdx.x * blockDim.x + threadIdx.x;
    if (v >= n) return;
    float a[C];
#pragma unroll
    for (int ci = 0; ci < C; ci++) a[ci] = x[(long)ci * n + v];
    float4* dp = reinterpret_cast<float4*>(xt + (long)v * C);
    dp[0] = make_float4(a[0], a[1], a[2], a[3]);
    dp[1] = make_float4(a[4], a[5], a[6], a[7]);
    dp[2] = make_float4(a[8], a[9], a[10], a[11]);
    dp[3] = make_float4(a[12], a[13], a[14], a[15]);
}

// ---- NDHWC -> NCDHW (stage outputs into d_out) ----
__global__ void to_ncdhw_kernel(const float* __restrict__ src, float* __restrict__ dst, int n) {
    int v = blockIdx.x * blockDim.x + threadIdx.x;
    if (v >= n) return;
    const float4* sp = reinterpret_cast<const float4*>(src + (long)v * C);
    float4 q0 = sp[0], q1 = sp[1], q2 = sp[2], q3 = sp[3];
    dst[0L * n + v] = q0.x;  dst[1L * n + v] = q0.y;
    dst[2L * n + v] = q0.z;  dst[3L * n + v] = q0.w;
    dst[4L * n + v] = q1.x;  dst[5L * n + v] = q1.y;
    dst[6L * n + v] = q1.z;  dst[7L * n + v] = q1.w;
    dst[8L * n + v] = q2.x;  dst[9L * n + v] = q2.y;
    dst[10L * n + v] = q2.z; dst[11L * n + v] = q2.w;
    dst[12L * n + v] = q3.x; dst[13L * n + v] = q3.y;
    dst[14L * n + v] = q3.z; dst[15L * n + v] = q3.w;
}

// ---- ordered compaction: counts -> scan -> scatter ----
__global__ void count_kernel(const int* __restrict__ mi, int* __restrict__ counts, int n) {
    int i = blockIdx.x * 256 + threadIdx.x;
    int act = (i < n) && (mi[i] == 0);
    unsigned long long b = __ballot(act);
    __shared__ int wsum[4];
    int wid = threadIdx.x >> 6, lane = threadIdx.x & 63;
    if (lane == 0) wsum[wid] = __popcll(b);
    __syncthreads();
    if (threadIdx.x == 0) counts[blockIdx.x] = wsum[0] + wsum[1] + wsum[2] + wsum[3];
}

__global__ void scan_kernel(const int* __restrict__ counts, int* __restrict__ offsets,
                            int* __restrict__ nact, int nb) {
    __shared__ int s[256];
    int t = threadIdx.x;
    const int CH = (nb + 255) / 256;
    int base = t * CH, sum = 0;
    for (int j = 0; j < CH; j++)
        if (base + j < nb) sum += counts[base + j];
    s[t] = sum;
    __syncthreads();
    for (int off = 1; off < 256; off <<= 1) {
        int v = (t >= off) ? s[t - off] : 0;
        __syncthreads();
        s[t] += v;
        __syncthreads();
    }
    int run = s[t] - sum;  // exclusive base
    for (int j = 0; j < CH; j++) {
        if (base + j < nb) {
            offsets[base + j] = run;
            run += counts[base + j];
        }
    }
    if (t == 255) *nact = s[255];
}

__global__ void scatter_kernel(const int* __restrict__ mi, const int* __restrict__ offsets,
                               int* __restrict__ list, int n, int cap) {
    int i = blockIdx.x * 256 + threadIdx.x;
    int act = (i < n) && (mi[i] == 0);
    unsigned long long b = __ballot(act);
    __shared__ int wsum[4];
    int wid = threadIdx.x >> 6, lane = threadIdx.x & 63;
    if (lane == 0) wsum[wid] = __popcll(b);
    __syncthreads();
    int wbase = 0;
    for (int w = 0; w < wid; w++) wbase += wsum[w];
    int prefix = __popcll(b & ((1ull << lane) - 1));
    if (act) {
        int pos = offsets[blockIdx.x] + wbase + prefix;
        if (pos < cap) list[pos] = i;
    }
}

// ---- mask maxpool (2x2x2 stride, 3^3 window) ----
template <bool FROM_INT>
__global__ void pool_mask_kernel(const int* __restrict__ mi, const float* __restrict__ mf,
                                 float* __restrict__ mout, int Din, int Dout) {
    int i = blockIdx.x * blockDim.x + threadIdx.x;
    int n = Dout * Dout * Dout;
    if (i >= n) return;
    int x = i % Dout, y = (i / Dout) % Dout, z = i / (Dout * Dout);
    float v = 0.f;
    for (int kz = 0; kz < 3; kz++) {
        int zz = 2 * z - 1 + kz;
        if (zz < 0 || zz >= Din) continue;
        for (int ky = 0; ky < 3; ky++) {
            int yy = 2 * y - 1 + ky;
            if (yy < 0 || yy >= Din) continue;
            for (int kx = 0; kx < 3; kx++) {
                int xx = 2 * x - 1 + kx;
                if (xx < 0 || xx >= Din) continue;
                long idx = ((long)zz * Din + yy) * Din + xx;
                float mv = FROM_INT ? ((mi[idx] == 0) ? 1.f : 0.f) : mf[idx];
                v = fmaxf(v, mv);
            }
        }
    }
    mout[i] = v;
}

// ---- conv in NDHWC; 1 voxel x 16 co per thread; NO LDS ----
// Weights read with wave-uniform indices -> scalar path (SGPR broadcast into
// v_fma), zero LDS traffic. Flattened tap loop, 2-deep software pipeline with
// named A/B float4 regs (compile-time indexing only; #pragma unroll 1 keeps
// exactly one prefetch in flight -> no regalloc blowup).
#define F4ROW(AV, CI)                                         \
    {                                                         \
        const float* wr_ = wp_ + (CI) * C;                    \
        _Pragma("unroll") for (int co_ = 0; co_ < C; co_++) { \
            acc[co_] += (AV) * wr_[co_];                      \
        }                                                     \
    }
#define FMAS(T0, T1, T2, T3, T)                     \
    {                                               \
        const float* wp_ = Wl + (T) * (C * C);      \
        F4ROW(T0.x, 0) F4ROW(T0.y, 1)               \
        F4ROW(T0.z, 2) F4ROW(T0.w, 3)               \
        F4ROW(T1.x, 4) F4ROW(T1.y, 5)               \
        F4ROW(T1.z, 6) F4ROW(T1.w, 7)               \
        F4ROW(T2.x, 8) F4ROW(T2.y, 9)               \
        F4ROW(T2.z, 10) F4ROW(T2.w, 11)             \
        F4ROW(T3.x, 12) F4ROW(T3.y, 13)             \
        F4ROW(T3.z, 14) F4ROW(T3.w, 15)             \
    }

template <int STRIDE, bool SPARSE>
__global__ __launch_bounds__(CBS) void conv_kernel(
    const float* __restrict__ in, float* __restrict__ out,
    const float* __restrict__ mask, const int* __restrict__ list,
    const int* __restrict__ nact, const float* __restrict__ Wl,
    const float* __restrict__ bs, const float* __restrict__ bb,
    int Din, int Dout) {
    int n = Dout * Dout * Dout;
    int nv = SPARSE ? *nact : n;
    if (SPARSE && nv > LISTCAP) nv = LISTCAP;
    int s0 = blockIdx.x * CBS + threadIdx.x;
    if ((int)(blockIdx.x * CBS) >= nv) return;  // uniform whole-block early exit

    bool val = s0 < nv;
    int v = 0;
    if (SPARSE) {
        if (val) v = list[s0];
    } else {
        v = val ? s0 : 0;
    }
    int x = v % Dout, y = (v / Dout) % Dout, z = v / (Dout * Dout);
    float mk = SPARSE ? 1.f : (val ? mask[v] : 0.f);

    float acc[C];
#pragma unroll
    for (int co = 0; co < C; co++) acc[co] = 0.f;

    const float4 z4 = make_float4(0.f, 0.f, 0.f, 0.f);
    auto taploads = [&](int t, float4& T0, float4& T1, float4& T2, float4& T3) {
        int kz = t / 9;
        int r = t - kz * 9;
        int ky = r / 3;
        int kx = r - ky * 3;
        int zz = STRIDE * z - 1 + kz;
        int yy = STRIDE * y - 1 + ky;
        int xx = STRIDE * x - 1 + kx;
        bool ok = ((unsigned)zz < (unsigned)Din) && ((unsigned)yy < (unsigned)Din) &&
                  ((unsigned)xx < (unsigned)Din);
        if (ok) {
            const float4* p =
                reinterpret_cast<const float4*>(in + (long)((zz * Din + yy) * Din + xx) * C);
            T0 = p[0];
            T1 = p[1];
            T2 = p[2];
            T3 = p[3];
        } else {
            T0 = z4; T1 = z4; T2 = z4; T3 = z4;
        }
    };

    float4 A0, A1, A2, A3, B0, B1, B2, B3;
    taploads(0, A0, A1, A2, A3);
#pragma unroll 1
    for (int t = 0; t + 2 <= TAPS; t += 2) {
        taploads(t + 1, B0, B1, B2, B3);
        FMAS(A0, A1, A2, A3, t)
        taploads(t + 2, A0, A1, A2, A3);  // t+2 <= 26 always (t <= 24), tap 26 valid
        FMAS(B0, B1, B2, B3, t + 1)
    }
    FMAS(A0, A1, A2, A3, TAPS - 1)  // tap 26

    if (val) {
        float r[C];
#pragma unroll
        for (int co = 0; co < C; co++)
            r[co] = fmaxf(acc[co] * bs[co] + bb[co], 0.f) * mk;
        float4* o4 = reinterpret_cast<float4*>(out + (long)v * C);
        o4[0] = make_float4(r[0], r[1], r[2], r[3]);
        o4[1] = make_float4(r[4], r[5], r[6], r[7]);
        o4[2] = make_float4(r[8], r[9], r[10], r[11]);
        o4[3] = make_float4(r[12], r[13], r[14], r[15]);
    }
}

extern "C" void kernel_launch(void* const* d_in, const int* in_sizes, int n_in,
                              void* d_out, int out_size, void* d_ws, size_t ws_size,
                              hipStream_t stream) {
    const float* x = (const float*)d_in[0];
    const int* mask_idx = (const int*)d_in[1];
    const float* W = (const float*)d_in[2];
    const float* bs = (const float*)d_in[3];
    const float* bb = (const float*)d_in[4];
    float* out = (float*)d_out;
    float* ws = (float*)d_ws;

    const int n96 = 96 * 96 * 96;  // 884736
    const int n48 = 48 * 48 * 48;  // 110592
    const int n24 = 24 * 24 * 24;  // 13824
    const int n12 = 12 * 12 * 12;  // 1728
    const int n6 = 6 * 6 * 6;      // 216
    const int NB = (n96 + 255) / 256;  // 3456

    float* P0 = ws;                  // xt, then ping-pong
    float* P1 = P0 + (long)C * n96;  // ping-pong (pre-zeroed for sparse scatter)
    float* m48 = P1 + (long)C * n96;
    float* m24 = m48 + n48;
    float* m12 = m24 + n24;
    float* m6 = m12 + n12;
    float* Wt = m6 + n6;
    int* list = (int*)(Wt + (long)NCONV * TAPS * C * C);
    int* counts = list + LISTCAP;
    int* offsets = counts + NB;
    int* nact = offsets + NB;

    const int BS = 256;
    auto blk = [&](long t) { return dim3((unsigned)((t + BS - 1) / BS)); };
    auto cblk = [&](long nvox) { return dim3((unsigned)((nvox + CBS - 1) / CBS)); };

    hipMemsetAsync(P1, 0, (long)C * n96 * sizeof(float), stream);
    hipLaunchKernelGGL(transpose_w_kernel, blk(NCONV * TAPS * C * C), dim3(BS), 0, stream, W, Wt);
    hipLaunchKernelGGL(transpose_in_kernel, blk(n96), dim3(BS), 0, stream, x, P0, n96);
    hipLaunchKernelGGL(count_kernel, dim3(NB), dim3(BS), 0, stream, mask_idx, counts, n96);
    hipLaunchKernelGGL(scan_kernel, dim3(1), dim3(BS), 0, stream, counts, offsets, nact, NB);
    hipLaunchKernelGGL(scatter_kernel, dim3(NB), dim3(BS), 0, stream, mask_idx, offsets, list,
                       n96, LISTCAP);

    auto sconv = [&](const float* in, float* op, int layer) {
        hipLaunchKernelGGL((conv_kernel<1, true>), cblk(LISTCAP), dim3(CBS), 0, stream,
                           in, op, (const float*)nullptr, list, nact,
                           Wt + (long)layer * TAPS * C * C, bs + layer * C, bb + layer * C, 96, 96);
    };
    auto subm = [&](const float* in, float* op, const float* m, int layer, int D) {
        int n = D * D * D;
        hipLaunchKernelGGL((conv_kernel<1, false>), cblk(n), dim3(CBS), 0, stream,
                           in, op, m, list, nact, Wt + (long)layer * TAPS * C * C,
                           bs + layer * C, bb + layer * C, D, D);
    };
    auto down = [&](const float* in, float* op, const float* m, int layer, int Dout) {
        int n = Dout * Dout * Dout;
        hipLaunchKernelGGL((conv_kernel<2, false>), cblk(n), dim3(CBS), 0, stream,
                           in, op, m, list, nact, Wt + (long)layer * TAPS * C * C,
                           bs + layer * C, bb + layer * C, 2 * Dout, Dout);
    };

    // masks
    hipLaunchKernelGGL((pool_mask_kernel<true>), blk(n48), dim3(BS), 0, stream,
                       mask_idx, (const float*)nullptr, m48, 96, 48);
    hipLaunchKernelGGL((pool_mask_kernel<false>), blk(n24), dim3(BS), 0, stream,
                       (const int*)nullptr, m48, m24, 48, 24);
    hipLaunchKernelGGL((pool_mask_kernel<false>), blk(n12), dim3(BS), 0, stream,
                       (const int*)nullptr, m24, m12, 24, 12);
    hipLaunchKernelGGL((pool_mask_kernel<false>), blk(n6), dim3(BS), 0, stream,
                       (const int*)nullptr, m12, m6, 12, 6);

    // Stage @96 (sparse). L0: P0(xt) -> P1 (zeroed). L1: P1 -> P0 (inactive already 0 from x*mask).
    sconv(P0, P1, 0);
    sconv(P1, P0, 1);
    // 48 level (dense, ~94% mask)
    down(P0, P1, m48, 2, 48);
    subm(P1, P0, m48, 3, 48);
    subm(P0, P1, m48, 4, 48);  // net1 in P1
    hipLaunchKernelGGL(to_ncdhw_kernel, blk(n48), dim3(BS), 0, stream, P1, out, n48);
    // 24 level
    down(P1, P0, m24, 5, 24);
    subm(P0, P1, m24, 6, 24);
    subm(P1, P0, m24, 7, 24);
    subm(P0, P1, m24, 8, 24);  // net2 in P1
    hipLaunchKernelGGL(to_ncdhw_kernel, blk(n24), dim3(BS), 0, stream, P1, out + (long)C * n48, n24);
    // 12 level
    down(P1, P0, m12, 9, 12);
    subm(P0, P1, m12, 10, 12);
    subm(P1, P0, m12, 11, 12);
    subm(P0, P1, m12, 12, 12);  // net3 in P1
    hipLaunchKernelGGL(to_ncdhw_kernel, blk(n12), dim3(BS), 0, stream, P1,
                       out + (long)C * (n48 + n24), n12);
    // 6 level
    down(P1, P0, m6, 13, 6);
    subm(P0, P1, m6, 14, 6);
    subm(P1, P0, m6, 15, 6);
    subm(P0, P1, m6, 16, 6);  // net4 in P1
    hipLaunchKernelGGL(to_ncdhw_kernel, blk(n6), dim3(BS), 0, stream, P1,
                       out + (long)C * (n48 + n24 + n12), n6);
}

// Round 9
// 747.301 us; speedup vs baseline: 1.7584x; 1.7584x over previous
//
#include <hip/hip_runtime.h>

#define C 16
#define TAPS 27
#define NCONV 17
#define LISTCAP 98304   // >> expected ~88.5K actives

// ---- weight prep: W[l][co][ci][tap] -> Wq[l][cq][tap][ci][4]  (co = cq*4+j) ----
__global__ void wq_kernel(const float* __restrict__ W, float* __restrict__ Wq) {
    int i = blockIdx.x * blockDim.x + threadIdx.x;
    const int total = NCONV * 4 * TAPS * C * 4;
    if (i >= total) return;
    int j = i & 3;
    int ci = (i >> 2) & 15;
    int t = (i >> 6) % TAPS;
    int rest = (i >> 6) / TAPS;
    int cq = rest & 3;
    int l = rest >> 2;
    int co = cq * 4 + j;
    Wq[i] = W[(((l * C + co) * C + ci) * TAPS) + t];
}

// ---- x: NCDHW -> NDHWC ----
__global__ void transpose_in_kernel(const float* __restrict__ x, float* __restrict__ xt, int n) {
    int v = blockIdx.x * blockDim.x + threadIdx.x;
    if (v >= n) return;
    float a[C];
#pragma unroll
    for (int ci = 0; ci < C; ci++) a[ci] = x[(long)ci * n + v];
    float4* dp = reinterpret_cast<float4*>(xt + (long)v * C);
    dp[0] = make_float4(a[0], a[1], a[2], a[3]);
    dp[1] = make_float4(a[4], a[5], a[6], a[7]);
    dp[2] = make_float4(a[8], a[9], a[10], a[11]);
    dp[3] = make_float4(a[12], a[13], a[14], a[15]);
}

// ---- NDHWC -> NCDHW (stage outputs into d_out) ----
__global__ void to_ncdhw_kernel(const float* __restrict__ src, float* __restrict__ dst, int n) {
    int v = blockIdx.x * blockDim.x + threadIdx.x;
    if (v >= n) return;
    const float4* sp = reinterpret_cast<const float4*>(src + (long)v * C);
    float4 q0 = sp[0], q1 = sp[1], q2 = sp[2], q3 = sp[3];
    dst[0L * n + v] = q0.x;  dst[1L * n + v] = q0.y;
    dst[2L * n + v] = q0.z;  dst[3L * n + v] = q0.w;
    dst[4L * n + v] = q1.x;  dst[5L * n + v] = q1.y;
    dst[6L * n + v] = q1.z;  dst[7L * n + v] = q1.w;
    dst[8L * n + v] = q2.x;  dst[9L * n + v] = q2.y;
    dst[10L * n + v] = q2.z; dst[11L * n + v] = q2.w;
    dst[12L * n + v] = q3.x; dst[13L * n + v] = q3.y;
    dst[14L * n + v] = q3.z; dst[15L * n + v] = q3.w;
}

// ---- ordered compaction: counts -> scan -> scatter ----
__global__ void count_kernel(const int* __restrict__ mi, int* __restrict__ counts, int n) {
    int i = blockIdx.x * 256 + threadIdx.x;
    int act = (i < n) && (mi[i] == 0);
    unsigned long long b = __ballot(act);
    __shared__ int wsum[4];
    int wid = threadIdx.x >> 6, lane = threadIdx.x & 63;
    if (lane == 0) wsum[wid] = __popcll(b);
    __syncthreads();
    if (threadIdx.x == 0) counts[blockIdx.x] = wsum[0] + wsum[1] + wsum[2] + wsum[3];
}

__global__ void scan_kernel(const int* __restrict__ counts, int* __restrict__ offsets,
                            int* __restrict__ nact, int nb) {
    __shared__ int s[256];
    int t = threadIdx.x;
    const int CH = (nb + 255) / 256;
    int base = t * CH, sum = 0;
    for (int j = 0; j < CH; j++)
        if (base + j < nb) sum += counts[base + j];
    s[t] = sum;
    __syncthreads();
    for (int off = 1; off < 256; off <<= 1) {
        int v = (t >= off) ? s[t - off] : 0;
        __syncthreads();
        s[t] += v;
        __syncthreads();
    }
    int run = s[t] - sum;  // exclusive base
    for (int j = 0; j < CH; j++) {
        if (base + j < nb) {
            offsets[base + j] = run;
            run += counts[base + j];
        }
    }
    if (t == 255) *nact = s[255];
}

__global__ void scatter_kernel(const int* __restrict__ mi, const int* __restrict__ offsets,
                               int* __restrict__ list, int n, int cap) {
    int i = blockIdx.x * 256 + threadIdx.x;
    int act = (i < n) && (mi[i] == 0);
    unsigned long long b = __ballot(act);
    __shared__ int wsum[4];
    int wid = threadIdx.x >> 6, lane = threadIdx.x & 63;
    if (lane == 0) wsum[wid] = __popcll(b);
    __syncthreads();
    int wbase = 0;
    for (int w = 0; w < wid; w++) wbase += wsum[w];
    int prefix = __popcll(b & ((1ull << lane) - 1));
    if (act) {
        int pos = offsets[blockIdx.x] + wbase + prefix;
        if (pos < cap) list[pos] = i;
    }
}

// ---- mask maxpool (2x2x2 stride, 3^3 window) ----
template <bool FROM_INT>
__global__ void pool_mask_kernel(const int* __restrict__ mi, const float* __restrict__ mf,
                                 float* __restrict__ mout, int Din, int Dout) {
    int i = blockIdx.x * blockDim.x + threadIdx.x;
    int n = Dout * Dout * Dout;
    if (i >= n) return;
    int x = i % Dout, y = (i / Dout) % Dout, z = i / (Dout * Dout);
    float v = 0.f;
    for (int kz = 0; kz < 3; kz++) {
        int zz = 2 * z - 1 + kz;
        if (zz < 0 || zz >= Din) continue;
        for (int ky = 0; ky < 3; ky++) {
            int yy = 2 * y - 1 + ky;
            if (yy < 0 || yy >= Din) continue;
            for (int kx = 0; kx < 3; kx++) {
                int xx = 2 * x - 1 + kx;
                if (xx < 0 || xx >= Din) continue;
                long idx = ((long)zz * Din + yy) * Din + xx;
                float mv = FROM_INT ? ((mi[idx] == 0) ? 1.f : 0.f) : mf[idx];
                v = fmaxf(v, mv);
            }
        }
    }
    mout[i] = v;
}

// ---- conv in NDHWC; block = 64 voxels x 4 waves; wave w -> co quad w ----
// Weights: Wq[cq][tap][ci][4], address chain rooted at readfirstlane(cq) ->
// provably wave-uniform -> s_load broadcasts (SGPR operand in v_fma). No LDS.
// Inputs: 4x float4 per tap per lane, 2-deep prefetch (r8-proven no-spill).
#define WROW(AV, CI)                       \
    acc0 += (AV) * wt_[(CI) * 4 + 0];      \
    acc1 += (AV) * wt_[(CI) * 4 + 1];      \
    acc2 += (AV) * wt_[(CI) * 4 + 2];      \
    acc3 += (AV) * wt_[(CI) * 4 + 3];

#define FMAS(T0, T1, T2, T3, T)                      \
    {                                                \
        const float* wt_ = wp + (T) * (C * 4);       \
        WROW(T0.x, 0) WROW(T0.y, 1)                  \
        WROW(T0.z, 2) WROW(T0.w, 3)                  \
        WROW(T1.x, 4) WROW(T1.y, 5)                  \
        WROW(T1.z, 6) WROW(T1.w, 7)                  \
        WROW(T2.x, 8) WROW(T2.y, 9)                  \
        WROW(T2.z, 10) WROW(T2.w, 11)                \
        WROW(T3.x, 12) WROW(T3.y, 13)                \
        WROW(T3.z, 14) WROW(T3.w, 15)                \
    }

template <int STRIDE, bool SPARSE>
__global__ __launch_bounds__(256) void conv_kernel(
    const float* __restrict__ in, float* __restrict__ out,
    const float* __restrict__ mask, const int* __restrict__ list,
    const int* __restrict__ nact, const float* __restrict__ Wq,
    const float* __restrict__ bs, const float* __restrict__ bb,
    int Din, int Dout) {
    int n = Dout * Dout * Dout;
    int nv = SPARSE ? *nact : n;
    if (SPARSE && nv > LISTCAP) nv = LISTCAP;
    if ((int)(blockIdx.x * 64) >= nv) return;  // uniform whole-block early exit

    int lane = threadIdx.x & 63;
    int cq = __builtin_amdgcn_readfirstlane(threadIdx.x >> 6);  // 0..3, uniform
    const float* wp = Wq + cq * (TAPS * C * 4);

    int s0 = blockIdx.x * 64 + lane;
    bool val = s0 < nv;
    int v = 0;
    if (SPARSE) {
        if (val) v = list[s0];
    } else {
        v = val ? s0 : 0;
    }
    int x = v % Dout, y = (v / Dout) % Dout, z = v / (Dout * Dout);
    float mk = SPARSE ? 1.f : (val ? mask[v] : 0.f);

    float acc0 = 0.f, acc1 = 0.f, acc2 = 0.f, acc3 = 0.f;

    const float4 z4 = make_float4(0.f, 0.f, 0.f, 0.f);
    auto taploads = [&](int t, float4& T0, float4& T1, float4& T2, float4& T3) {
        int kz = t / 9;
        int r = t - kz * 9;
        int ky = r / 3;
        int kx = r - ky * 3;
        int zz = STRIDE * z - 1 + kz;
        int yy = STRIDE * y - 1 + ky;
        int xx = STRIDE * x - 1 + kx;
        bool ok = ((unsigned)zz < (unsigned)Din) && ((unsigned)yy < (unsigned)Din) &&
                  ((unsigned)xx < (unsigned)Din);
        if (ok) {
            const float4* p =
                reinterpret_cast<const float4*>(in + (long)((zz * Din + yy) * Din + xx) * C);
            T0 = p[0];
            T1 = p[1];
            T2 = p[2];
            T3 = p[3];
        } else {
            T0 = z4; T1 = z4; T2 = z4; T3 = z4;
        }
    };

    float4 A0, A1, A2, A3, B0, B1, B2, B3;
    taploads(0, A0, A1, A2, A3);
#pragma unroll 1
    for (int t = 0; t + 2 <= TAPS; t += 2) {
        taploads(t + 1, B0, B1, B2, B3);
        FMAS(A0, A1, A2, A3, t)
        taploads(t + 2, A0, A1, A2, A3);  // t+2 <= 26 (t <= 24): tap 26 valid
        FMAS(B0, B1, B2, B3, t + 1)
    }
    FMAS(A0, A1, A2, A3, TAPS - 1)  // tap 26

    if (val) {
        int cob = cq * 4;
        float r0 = fmaxf(acc0 * bs[cob + 0] + bb[cob + 0], 0.f) * mk;
        float r1 = fmaxf(acc1 * bs[cob + 1] + bb[cob + 1], 0.f) * mk;
        float r2 = fmaxf(acc2 * bs[cob + 2] + bb[cob + 2], 0.f) * mk;
        float r3 = fmaxf(acc3 * bs[cob + 3] + bb[cob + 3], 0.f) * mk;
        float4* o4 = reinterpret_cast<float4*>(out + (long)v * C + cob);
        *o4 = make_float4(r0, r1, r2, r3);
    }
}

extern "C" void kernel_launch(void* const* d_in, const int* in_sizes, int n_in,
                              void* d_out, int out_size, void* d_ws, size_t ws_size,
                              hipStream_t stream) {
    const float* x = (const float*)d_in[0];
    const int* mask_idx = (const int*)d_in[1];
    const float* W = (const float*)d_in[2];
    const float* bs = (const float*)d_in[3];
    const float* bb = (const float*)d_in[4];
    float* out = (float*)d_out;
    float* ws = (float*)d_ws;

    const int n96 = 96 * 96 * 96;  // 884736
    const int n48 = 48 * 48 * 48;  // 110592
    const int n24 = 24 * 24 * 24;  // 13824
    const int n12 = 12 * 12 * 12;  // 1728
    const int n6 = 6 * 6 * 6;      // 216
    const int NB = (n96 + 255) / 256;  // 3456

    float* P0 = ws;                  // xt, then ping-pong
    float* P1 = P0 + (long)C * n96;  // ping-pong (pre-zeroed for sparse scatter)
    float* m48 = P1 + (long)C * n96;
    float* m24 = m48 + n48;
    float* m12 = m24 + n24;
    float* m6 = m12 + n12;
    float* Wq = m6 + n6;             // [l][4][27][16][4]
    int* list = (int*)(Wq + (long)NCONV * 4 * TAPS * C * 4);
    int* counts = list + LISTCAP;
    int* offsets = counts + NB;
    int* nact = offsets + NB;

    const int BS = 256;
    auto blk = [&](long t) { return dim3((unsigned)((t + BS - 1) / BS)); };
    auto cblk = [&](long nvox) { return dim3((unsigned)((nvox + 63) / 64)); };

    hipMemsetAsync(P1, 0, (long)C * n96 * sizeof(float), stream);
    hipLaunchKernelGGL(wq_kernel, blk(NCONV * 4 * TAPS * C * 4), dim3(BS), 0, stream, W, Wq);
    hipLaunchKernelGGL(transpose_in_kernel, blk(n96), dim3(BS), 0, stream, x, P0, n96);
    hipLaunchKernelGGL(count_kernel, dim3(NB), dim3(BS), 0, stream, mask_idx, counts, n96);
    hipLaunchKernelGGL(scan_kernel, dim3(1), dim3(BS), 0, stream, counts, offsets, nact, NB);
    hipLaunchKernelGGL(scatter_kernel, dim3(NB), dim3(BS), 0, stream, mask_idx, offsets, list,
                       n96, LISTCAP);

    auto sconv = [&](const float* in, float* op, int layer) {
        hipLaunchKernelGGL((conv_kernel<1, true>), cblk(LISTCAP), dim3(BS), 0, stream,
                           in, op, (const float*)nullptr, list, nact,
                           Wq + (long)layer * 4 * TAPS * C * 4, bs + layer * C, bb + layer * C,
                           96, 96);
    };
    auto subm = [&](const float* in, float* op, const float* m, int layer, int D) {
        int n = D * D * D;
        hipLaunchKernelGGL((conv_kernel<1, false>), cblk(n), dim3(BS), 0, stream,
                           in, op, m, list, nact, Wq + (long)layer * 4 * TAPS * C * 4,
                           bs + layer * C, bb + layer * C, D, D);
    };
    auto down = [&](const float* in, float* op, const float* m, int layer, int Dout) {
        int n = Dout * Dout * Dout;
        hipLaunchKernelGGL((conv_kernel<2, false>), cblk(n), dim3(BS), 0, stream,
                           in, op, m, list, nact, Wq + (long)layer * 4 * TAPS * C * 4,
                           bs + layer * C, bb + layer * C, 2 * Dout, Dout);
    };

    // masks
    hipLaunchKernelGGL((pool_mask_kernel<true>), blk(n48), dim3(BS), 0, stream,
                       mask_idx, (const float*)nullptr, m48, 96, 48);
    hipLaunchKernelGGL((pool_mask_kernel<false>), blk(n24), dim3(BS), 0, stream,
                       (const int*)nullptr, m48, m24, 48, 24);
    hipLaunchKernelGGL((pool_mask_kernel<false>), blk(n12), dim3(BS), 0, stream,
                       (const int*)nullptr, m24, m12, 24, 12);
    hipLaunchKernelGGL((pool_mask_kernel<false>), blk(n6), dim3(BS), 0, stream,
                       (const int*)nullptr, m12, m6, 12, 6);

    // Stage @96 (sparse). L0: P0(xt) -> P1 (zeroed). L1: P1 -> P0 (inactive already 0 from x*mask).
    sconv(P0, P1, 0);
    sconv(P1, P0, 1);
    // 48 level (dense, ~94% mask)
    down(P0, P1, m48, 2, 48);
    subm(P1, P0, m48, 3, 48);
    subm(P0, P1, m48, 4, 48);  // net1 in P1
    hipLaunchKernelGGL(to_ncdhw_kernel, blk(n48), dim3(BS), 0, stream, P1, out, n48);
    // 24 level
    down(P1, P0, m24, 5, 24);
    subm(P0, P1, m24, 6, 24);
    subm(P1, P0, m24, 7, 24);
    subm(P0, P1, m24, 8, 24);  // net2 in P1
    hipLaunchKernelGGL(to_ncdhw_kernel, blk(n24), dim3(BS), 0, stream, P1, out + (long)C * n48, n24);
    // 12 level
    down(P1, P0, m12, 9, 12);
    subm(P0, P1, m12, 10, 12);
    subm(P1, P0, m12, 11, 12);
    subm(P0, P1, m12, 12, 12);  // net3 in P1
    hipLaunchKernelGGL(to_ncdhw_kernel, blk(n12), dim3(BS), 0, stream, P1,
                       out + (long)C * (n48 + n24), n12);
    // 6 level
    down(P1, P0, m6, 13, 6);
    subm(P0, P1, m6, 14, 6);
    subm(P1, P0, m6, 15, 6);
    subm(P0, P1, m6, 16, 6);  // net4 in P1
    hipLaunchKernelGGL(to_ncdhw_kernel, blk(n6), dim3(BS), 0, stream, P1,
                       out + (long)C * (n48 + n24 + n12), n6);
}